// Round 4
// baseline (482.833 us; speedup 1.0000x reference)
//
#include <hip/hip_runtime.h>
#include <cmath>

#define NB 8
#define NPTS 2048
#define NE (NB * NPTS)
#define THREADS 256
#define RP 8              // row PAIRS per wave -> 16 rows/wave, 64 rows/block

typedef float v2f __attribute__((ext_vector_type(2)));

#if defined(__has_builtin)
#if __has_builtin(__builtin_amdgcn_exp2f)
#define FAST_EXP2(x) __builtin_amdgcn_exp2f(x)
#else
#define FAST_EXP2(x) exp2f(x)
#endif
#if __has_builtin(__builtin_amdgcn_logf)
#define FAST_LOG2(x) __builtin_amdgcn_logf(x)
#else
#define FAST_LOG2(x) log2f(x)
#endif
#else
#define FAST_EXP2(x) exp2f(x)
#define FAST_LOG2(x) log2f(x)
#endif

// One Sinkhorn "phase": for every row i of each batch (both sides),
//   softmin_eps(C, h)_i = -eps * LSE_j( h_j - C_ij/eps ),
// out = c_old*prev + c_new*softmin.
//
// C_ij/eps = (|x_i|^2 + |y_j|^2 - 2 x_i.y_j)/(2 eps).  Column constant
// hc_j = (h_j - |y_j|^2/(2eps))*log2e staged in LDS; row constant
// hr_i = -|x_i|^2/(2eps)*log2e added after the LSE.  Inner loop per
// row-pair: one v_pk_fma chain  t = pk_fma(rx, yx, pk_fma(ry, yy, hc)).
__global__ __launch_bounds__(THREADS, 2) void sinkhorn_phase(
    const float* __restrict__ x, const float* __restrict__ y,
    const float* __restrict__ loga, const float* __restrict__ logb,
    const float* __restrict__ f_prev, const float* __restrict__ g_prev,
    float* __restrict__ f_next, float* __restrict__ g_next,
    float eps, float inv_eps, float c_old, float c_new, int initPhase)
{
    __shared__ float4 tile[NPTS];  // {y.x, y.y, hc (log2 domain), pad}

    const int blk = blockIdx.x;
    const int side = blk >> 8;          // 256 blocks per side
    const int rblk = blk & 255;
    const int batch = rblk >> 5;        // 32 row-tiles (of 64 rows) per batch
    const int rowTile = rblk & 31;

    const float* rowPts; const float* colPts; const float* hlog;
    const float* hpot; const float* ownPrev; float* outPot;
    if (side == 0) { rowPts = x; colPts = y; hlog = logb; hpot = g_prev; ownPrev = f_prev; outPot = f_next; }
    else           { rowPts = y; colPts = x; hlog = loga; hpot = f_prev; ownPrev = g_prev; outPot = g_next; }

    const float LOG2E = 1.4426950408889634f;
    const float LN2 = 0.69314718055994531f;

    // Stage columns + log2-domain h-constant into LDS.
    const float2* cp2 = (const float2*)(colPts + (size_t)batch * NPTS * 2);
    const float* hl = hlog + (size_t)batch * NPTS;
    const float* pp = hpot + (size_t)batch * NPTS;
    for (int j = threadIdx.x; j < NPTS; j += THREADS) {
        float2 p = cp2[j];
        float hp = 0.0f;
        if (!initPhase) hp = pp[j] * inv_eps;
        float hcv = (hl[j] + hp
                     - 0.5f * inv_eps * fmaf(p.x, p.x, p.y * p.y)) * LOG2E;
        tile[j] = make_float4(p.x, p.y, hcv, 0.0f);
    }
    __syncthreads();

    const int lane = threadIdx.x & 63;
    const int wv = threadIdx.x >> 6;                 // 4 waves/block
    const int row0 = rowTile * 64 + wv * (2 * RP);
    const float2* rp2 = (const float2*)(rowPts + (size_t)batch * NPTS * 2) + row0;

    const float sc = inv_eps * LOG2E;
    v2f rx[RP], ry[RP], hr[RP];
    #pragma unroll
    for (int p = 0; p < RP; p++) {
        float2 p0 = rp2[2 * p];
        float2 p1 = rp2[2 * p + 1];
        rx[p] = (v2f){p0.x * sc, p1.x * sc};
        ry[p] = (v2f){p0.y * sc, p1.y * sc};
        hr[p] = (v2f){-0.5f * sc * fmaf(p0.x, p0.x, p0.y * p0.y),
                      -0.5f * sc * fmaf(p1.x, p1.x, p1.y * p1.y)};
    }

    // Pass 1: row maxima (log2 domain); 64 distinct j per wave-iter.
    v2f m[RP];
    #pragma unroll
    for (int p = 0; p < RP; p++) m[p] = (v2f){-3.4e38f, -3.4e38f};
    #pragma unroll 4
    for (int it = 0; it < NPTS / 64; it++) {
        float4 t4 = tile[(it << 6) + lane];
        v2f yx = (v2f){t4.x, t4.x};
        v2f yy = (v2f){t4.y, t4.y};
        v2f hc = (v2f){t4.z, t4.z};
        #pragma unroll
        for (int p = 0; p < RP; p++) {
            v2f t = __builtin_elementwise_fma(rx[p], yx,
                        __builtin_elementwise_fma(ry[p], yy, hc));
            m[p] = __builtin_elementwise_max(m[p], t);
        }
    }
    #pragma unroll
    for (int p = 0; p < RP; p++) {
        #pragma unroll
        for (int d = 32; d >= 1; d >>= 1) {
            v2f o = (v2f){__shfl_xor(m[p].x, d), __shfl_xor(m[p].y, d)};
            m[p] = __builtin_elementwise_max(m[p], o);
        }
    }

    // Pass 2: sum of exp2(t - m).
    v2f s[RP];
    #pragma unroll
    for (int p = 0; p < RP; p++) s[p] = (v2f){0.0f, 0.0f};
    #pragma unroll 4
    for (int it = 0; it < NPTS / 64; it++) {
        float4 t4 = tile[(it << 6) + lane];
        v2f yx = (v2f){t4.x, t4.x};
        v2f yy = (v2f){t4.y, t4.y};
        v2f hc = (v2f){t4.z, t4.z};
        #pragma unroll
        for (int p = 0; p < RP; p++) {
            v2f t = __builtin_elementwise_fma(rx[p], yx,
                        __builtin_elementwise_fma(ry[p], yy, hc));
            v2f d = t - m[p];
            s[p] += (v2f){FAST_EXP2(d.x), FAST_EXP2(d.y)};
        }
    }
    #pragma unroll
    for (int p = 0; p < RP; p++) {
        #pragma unroll
        for (int d = 32; d >= 1; d >>= 1) {
            s[p] += (v2f){__shfl_xor(s[p].x, d), __shfl_xor(s[p].y, d)};
        }
    }

    if (lane == 0) {
        const int idx0 = batch * NPTS + row0;
        #pragma unroll
        for (int p = 0; p < RP; p++) {
            float sm0 = -eps * LN2 * (hr[p].x + m[p].x + FAST_LOG2(s[p].x));
            float sm1 = -eps * LN2 * (hr[p].y + m[p].y + FAST_LOG2(s[p].y));
            outPot[idx0 + 2 * p]     = c_old * ownPrev[idx0 + 2 * p]     + c_new * sm0;
            outPot[idx0 + 2 * p + 1] = c_old * ownPrev[idx0 + 2 * p + 1] + c_new * sm1;
        }
    }
}

__global__ void log_precompute(const float* __restrict__ a, const float* __restrict__ b,
                               float* __restrict__ loga, float* __restrict__ logb, int n)
{
    int i = blockIdx.x * blockDim.x + threadIdx.x;
    if (i < n) {
        loga[i] = logf(a[i]);
        logb[i] = logf(b[i]);
    }
}

__global__ __launch_bounds__(1024) void loss_reduce(
    const float* __restrict__ a, const float* __restrict__ bw,
    const float* __restrict__ f, const float* __restrict__ g,
    float* __restrict__ out)
{
    float acc = 0.0f;
    for (int i = threadIdx.x; i < NE; i += 1024)
        acc += a[i] * f[i] + bw[i] * g[i];
    acc += __shfl_xor(acc, 32);
    acc += __shfl_xor(acc, 16);
    acc += __shfl_xor(acc, 8);
    acc += __shfl_xor(acc, 4);
    acc += __shfl_xor(acc, 2);
    acc += __shfl_xor(acc, 1);
    __shared__ float wsum[16];
    int wid = threadIdx.x >> 6;
    if ((threadIdx.x & 63) == 0) wsum[wid] = acc;
    __syncthreads();
    if (threadIdx.x < 16) {
        float v = wsum[threadIdx.x];
        v += __shfl_xor(v, 8, 16);
        v += __shfl_xor(v, 4, 16);
        v += __shfl_xor(v, 2, 16);
        v += __shfl_xor(v, 1, 16);
        if (threadIdx.x == 0) out[0] = v * (1.0f / NB);
    }
}

extern "C" void kernel_launch(void* const* d_in, const int* in_sizes, int n_in,
                              void* d_out, int out_size, void* d_ws, size_t ws_size,
                              hipStream_t stream)
{
    const float* a = (const float*)d_in[0];
    const float* x = (const float*)d_in[1];
    const float* b = (const float*)d_in[2];
    const float* y = (const float*)d_in[3];
    float* out = (float*)d_out;

    float* ws = (float*)d_ws;
    float* loga = ws + 0 * NE;
    float* logb = ws + 1 * NE;
    float* fA   = ws + 2 * NE;
    float* gA   = ws + 3 * NE;
    float* fB   = ws + 4 * NE;
    float* gB   = ws + 5 * NE;

    // eps annealing schedule (double on host, as in reference)
    double eps_list[32];
    int ne = 0;
    const double eps_final = 0.05 * 0.05;   // blur^p
    double eps = 2.0 * 2.0;                  // diameter^p
    while (eps > eps_final) { eps_list[ne++] = eps; eps *= 0.64; }  // scaling^p
    eps_list[ne++] = eps_final;              // ne == 18

    log_precompute<<<(NE + 255) / 256, 256, 0, stream>>>(a, b, loga, logb, NE);

    const float* fp = fA; const float* gp = gA;
    float* fn = fB; float* gn = gB;

    auto phase = [&](double e, float c_old, float c_new, int init) {
        sinkhorn_phase<<<512, THREADS, 0, stream>>>(
            x, y, loga, logb, fp, gp, fn, gn,
            (float)e, (float)(1.0 / e), c_old, c_new, init);
    };
    auto swapbuf = [&]() {
        const float* tf = fp; const float* tg = gp;
        fp = fn; gp = gn;
        fn = (float*)tf; gn = (float*)tg;
    };

    // init at eps0: f = softmin(eps0, C, log_b) etc., no potentials read
    phase(eps_list[0], 0.0f, 1.0f, 1);
    swapbuf();
    // annealed damped iterations
    for (int k = 0; k < ne; k++) {
        phase(eps_list[k], 0.5f, 0.5f, 0);
        swapbuf();
    }
    // final extrapolation at eps_final (no damping)
    phase(eps_list[ne - 1], 0.0f, 1.0f, 0);
    // result potentials are in fn, gn

    loss_reduce<<<1, 1024, 0, stream>>>(a, b, fn, gn, out);
}

// Round 5
// 364.717 us; speedup vs baseline: 1.3239x; 1.3239x over previous
//
#include <hip/hip_runtime.h>
#include <cmath>

#define NB 8
#define NPTS 2048
#define NE (NB * NPTS)
#define THREADS 512
#define RPW 8   // rows per wave

#if defined(__has_builtin)
#if __has_builtin(__builtin_amdgcn_exp2f)
#define FAST_EXP2(x) __builtin_amdgcn_exp2f(x)
#else
#define FAST_EXP2(x) exp2f(x)
#endif
#if __has_builtin(__builtin_amdgcn_logf)
#define FAST_LOG2(x) __builtin_amdgcn_logf(x)
#else
#define FAST_LOG2(x) log2f(x)
#endif
#else
#define FAST_EXP2(x) exp2f(x)
#define FAST_LOG2(x) log2f(x)
#endif

// ---- DPP wave64 reductions (VALU pipe only; result valid at lane 63) ----
// ctrl: 0xB1 quad_perm[1,0,3,2] (xor1), 0x4E quad_perm[2,3,0,1] (xor2),
// 0x141 ROW_HALF_MIRROR, 0x140 ROW_MIRROR, 0x142 ROW_BCAST15, 0x143 ROW_BCAST31.
template<int CTRL>
__device__ __forceinline__ float dpp_f(float v) {
    return __int_as_float(__builtin_amdgcn_update_dpp(
        __float_as_int(v), __float_as_int(v), CTRL, 0xF, 0xF, false));
}
__device__ __forceinline__ float wred_max(float v) {
    v = fmaxf(v, dpp_f<0xB1>(v));
    v = fmaxf(v, dpp_f<0x4E>(v));
    v = fmaxf(v, dpp_f<0x141>(v));
    v = fmaxf(v, dpp_f<0x140>(v));
    v = fmaxf(v, dpp_f<0x142>(v));
    v = fmaxf(v, dpp_f<0x143>(v));
    return v;  // lane 63 correct
}
__device__ __forceinline__ float wred_sum(float v) {
    v += dpp_f<0xB1>(v);
    v += dpp_f<0x4E>(v);
    v += dpp_f<0x141>(v);
    v += dpp_f<0x140>(v);
    v += dpp_f<0x142>(v);   // non-dest lanes double (old=v) but lane63 path is valid
    v += dpp_f<0x143>(v);
    return v;  // lane 63 correct
}

// One Sinkhorn "phase": softmin_eps(C,h) for all rows of both sides, damped.
// Fused single pass: s_r = sum_j exp2(t_rj - m_est_r) with m_est from the
// previous phase's stored LSE (scaled by eps ratio). Validation: s in
// (1e-30, 1e34) guarantees full fp32 precision (stabilizer within ~±100 of
// the true max in log2 domain); otherwise an exact 2-pass redo runs.
__global__ __launch_bounds__(THREADS, 4) void sinkhorn_phase(
    const float* __restrict__ x, const float* __restrict__ y,
    const float* __restrict__ loga, const float* __restrict__ logb,
    const float* __restrict__ f_prev, const float* __restrict__ g_prev,
    float* __restrict__ f_next, float* __restrict__ g_next,
    float* __restrict__ Ls,          // [2][NB][NPTS] log2-domain LSE store
    float eps, float inv_eps, float c_old, float c_new,
    float mscale, int initPhase)
{
    __shared__ float4 tile[NPTS];   // {y.x, y.y, hc(log2), pad}

    const int blk = blockIdx.x;
    const int side = blk >> 8;          // 256 blocks/side
    const int rblk = blk & 255;
    const int batch = rblk >> 5;        // 32 row-tiles (64 rows) per batch
    const int rowTile = rblk & 31;

    const float* rowPts; const float* colPts; const float* hlog;
    const float* hpot; const float* ownPrev; float* outPot;
    if (side == 0) { rowPts=x; colPts=y; hlog=logb; hpot=g_prev; ownPrev=f_prev; outPot=f_next; }
    else           { rowPts=y; colPts=x; hlog=loga; hpot=f_prev; ownPrev=g_prev; outPot=g_next; }

    const float LOG2E = 1.4426950408889634f;
    const float LN2 = 0.69314718055994531f;

    // Stage columns + log2-domain column constant into LDS.
    const float2* cp2 = (const float2*)(colPts + (size_t)batch*NPTS*2);
    const float* hl = hlog + (size_t)batch*NPTS;
    const float* pp = hpot + (size_t)batch*NPTS;
    for (int j = threadIdx.x; j < NPTS; j += THREADS) {
        float2 p = cp2[j];
        float hp = initPhase ? 0.0f : pp[j] * inv_eps;
        float hcv = (hl[j] + hp - 0.5f*inv_eps*fmaf(p.x, p.x, p.y*p.y)) * LOG2E;
        tile[j] = make_float4(p.x, p.y, hcv, 0.0f);
    }
    __syncthreads();

    const int lane = threadIdx.x & 63;
    const int wv = threadIdx.x >> 6;                 // 8 waves/block
    const int row0 = rowTile*64 + wv*RPW;
    const int gidx0 = batch*NPTS + row0;
    const float2* rp2 = (const float2*)(rowPts + (size_t)batch*NPTS*2) + row0;
    const float* Lp = Ls + side*NE + gidx0;

    const float sc = inv_eps * LOG2E;
    float rx[RPW], ry[RPW], hr[RPW], mest[RPW], s[RPW];
    #pragma unroll
    for (int r = 0; r < RPW; r++) {
        float2 p = rp2[r];
        rx[r] = p.x * sc;
        ry[r] = p.y * sc;
        hr[r] = -0.5f * sc * fmaf(p.x, p.x, p.y * p.y);
        // initPhase: m_est=200 forces redo -> exercises the exact fallback
        mest[r] = initPhase ? 200.0f : Lp[r] * mscale;
        s[r] = 0.0f;
    }

    // Fused pass: 4 VALU + 1 exp2 per (row, j) element.
    #pragma unroll 4
    for (int it = 0; it < NPTS/64; it++) {
        float4 t4 = tile[(it << 6) + lane];
        #pragma unroll
        for (int r = 0; r < RPW; r++) {
            float t = fmaf(rx[r], t4.x, fmaf(ry[r], t4.y, t4.z)) - mest[r];
            s[r] += FAST_EXP2(t);
        }
    }
    #pragma unroll
    for (int r = 0; r < RPW; r++) s[r] = wred_sum(s[r]);

    int bad = 0;
    if (lane == 63) {
        #pragma unroll
        for (int r = 0; r < RPW; r++)
            bad |= !(s[r] > 1e-30f && s[r] < 1e34f);
    }
    if (__any(bad)) {
        // Exact 2-pass redo (wave-local; tile unchanged, no barrier needed).
        float mm[RPW];
        #pragma unroll
        for (int r = 0; r < RPW; r++) mm[r] = -3.4e38f;
        #pragma unroll 4
        for (int it = 0; it < NPTS/64; it++) {
            float4 t4 = tile[(it << 6) + lane];
            #pragma unroll
            for (int r = 0; r < RPW; r++) {
                float t = fmaf(rx[r], t4.x, fmaf(ry[r], t4.y, t4.z)) - mest[r];
                mm[r] = fmaxf(mm[r], t);
            }
        }
        #pragma unroll
        for (int r = 0; r < RPW; r++) {
            mm[r] = wred_max(mm[r]);
            mm[r] = __shfl(mm[r], 63);   // broadcast true (shifted) max
            s[r] = 0.0f;
        }
        #pragma unroll 4
        for (int it = 0; it < NPTS/64; it++) {
            float4 t4 = tile[(it << 6) + lane];
            #pragma unroll
            for (int r = 0; r < RPW; r++) {
                float t = fmaf(rx[r], t4.x, fmaf(ry[r], t4.y, t4.z)) - mest[r];
                s[r] += FAST_EXP2(t - mm[r]);
            }
        }
        #pragma unroll
        for (int r = 0; r < RPW; r++) {
            s[r] = wred_sum(s[r]);
            mest[r] += mm[r];            // final L = mest + mm + log2(s)
        }
    }

    if (lane == 63) {
        #pragma unroll
        for (int r = 0; r < RPW; r++) {
            float L = mest[r] + FAST_LOG2(s[r]);          // log2-domain LSE
            float sm = -eps * LN2 * (hr[r] + L);          // softmin value
            outPot[gidx0 + r] = c_old * ownPrev[gidx0 + r] + c_new * sm;
            Ls[side*NE + gidx0 + r] = L;                  // estimator for next phase
        }
    }
}

__global__ void log_precompute(const float* __restrict__ a, const float* __restrict__ b,
                               float* __restrict__ loga, float* __restrict__ logb, int n)
{
    int i = blockIdx.x * blockDim.x + threadIdx.x;
    if (i < n) {
        loga[i] = logf(a[i]);
        logb[i] = logf(b[i]);
    }
}

__global__ __launch_bounds__(1024) void loss_reduce(
    const float* __restrict__ a, const float* __restrict__ bw,
    const float* __restrict__ f, const float* __restrict__ g,
    float* __restrict__ out)
{
    float acc = 0.0f;
    for (int i = threadIdx.x; i < NE; i += 1024)
        acc += a[i] * f[i] + bw[i] * g[i];
    acc += __shfl_xor(acc, 32);
    acc += __shfl_xor(acc, 16);
    acc += __shfl_xor(acc, 8);
    acc += __shfl_xor(acc, 4);
    acc += __shfl_xor(acc, 2);
    acc += __shfl_xor(acc, 1);
    __shared__ float wsum[16];
    int wid = threadIdx.x >> 6;
    if ((threadIdx.x & 63) == 0) wsum[wid] = acc;
    __syncthreads();
    if (threadIdx.x < 16) {
        float v = wsum[threadIdx.x];
        v += __shfl_xor(v, 8, 16);
        v += __shfl_xor(v, 4, 16);
        v += __shfl_xor(v, 2, 16);
        v += __shfl_xor(v, 1, 16);
        if (threadIdx.x == 0) out[0] = v * (1.0f / NB);
    }
}

extern "C" void kernel_launch(void* const* d_in, const int* in_sizes, int n_in,
                              void* d_out, int out_size, void* d_ws, size_t ws_size,
                              hipStream_t stream)
{
    const float* a = (const float*)d_in[0];
    const float* x = (const float*)d_in[1];
    const float* b = (const float*)d_in[2];
    const float* y = (const float*)d_in[3];
    float* out = (float*)d_out;

    float* ws = (float*)d_ws;
    float* loga = ws + 0 * NE;
    float* logb = ws + 1 * NE;
    float* fA   = ws + 2 * NE;
    float* gA   = ws + 3 * NE;
    float* fB   = ws + 4 * NE;
    float* gB   = ws + 5 * NE;
    float* Ls   = ws + 6 * NE;      // 2*NE floats

    // eps annealing schedule (host-side, as in reference)
    double eps_list[32];
    int ne = 0;
    const double eps_final = 0.05 * 0.05;   // blur^p
    double eps = 2.0 * 2.0;                  // diameter^p
    while (eps > eps_final) { eps_list[ne++] = eps; eps *= 0.64; }  // scaling^p
    eps_list[ne++] = eps_final;              // ne == 18

    log_precompute<<<(NE + 255) / 256, 256, 0, stream>>>(a, b, loga, logb, NE);

    const float* fp = fA; const float* gp = gA;
    float* fn = fB; float* gn = gB;

    auto phase = [&](double e, double e_prev, float c_old, float c_new, int init) {
        sinkhorn_phase<<<512, THREADS, 0, stream>>>(
            x, y, loga, logb, fp, gp, fn, gn, Ls,
            (float)e, (float)(1.0 / e), c_old, c_new,
            (float)(e_prev / e), init);
    };
    auto swapbuf = [&]() {
        const float* tf = fp; const float* tg = gp;
        fp = fn; gp = gn;
        fn = (float*)tf; gn = (float*)tg;
    };

    // init at eps0 (no potentials read; forced redo validates fallback path)
    phase(eps_list[0], eps_list[0], 0.0f, 1.0f, 1);
    swapbuf();
    // annealed damped iterations
    double e_prev = eps_list[0];
    for (int k = 0; k < ne; k++) {
        phase(eps_list[k], e_prev, 0.5f, 0.5f, 0);
        e_prev = eps_list[k];
        swapbuf();
    }
    // final extrapolation at eps_final (no damping)
    phase(eps_list[ne - 1], e_prev, 0.0f, 1.0f, 0);
    // result potentials are in fn, gn

    loss_reduce<<<1, 1024, 0, stream>>>(a, b, fn, gn, out);
}

// Round 6
// 337.138 us; speedup vs baseline: 1.4322x; 1.0818x over previous
//
#include <hip/hip_runtime.h>
#include <cmath>

#define NB 8
#define NPTS 2048
#define NE (NB * NPTS)
#define THREADS 512
#define RPW 4   // rows per wave -> 32 rows per block, 1024 blocks

#if defined(__has_builtin)
#if __has_builtin(__builtin_amdgcn_exp2f)
#define FAST_EXP2(x) __builtin_amdgcn_exp2f(x)
#else
#define FAST_EXP2(x) exp2f(x)
#endif
#if __has_builtin(__builtin_amdgcn_logf)
#define FAST_LOG2(x) __builtin_amdgcn_logf(x)
#else
#define FAST_LOG2(x) log2f(x)
#endif
#else
#define FAST_EXP2(x) exp2f(x)
#define FAST_LOG2(x) log2f(x)
#endif

// ---- DPP wave64 reductions (VALU pipe only; result valid at lane 63) ----
template<int CTRL>
__device__ __forceinline__ float dpp_f(float v) {
    return __int_as_float(__builtin_amdgcn_update_dpp(
        __float_as_int(v), __float_as_int(v), CTRL, 0xF, 0xF, false));
}
__device__ __forceinline__ float wred_max(float v) {
    v = fmaxf(v, dpp_f<0xB1>(v));
    v = fmaxf(v, dpp_f<0x4E>(v));
    v = fmaxf(v, dpp_f<0x141>(v));
    v = fmaxf(v, dpp_f<0x140>(v));
    v = fmaxf(v, dpp_f<0x142>(v));
    v = fmaxf(v, dpp_f<0x143>(v));
    return v;  // lane 63 correct
}
__device__ __forceinline__ float wred_sum(float v) {
    v += dpp_f<0xB1>(v);
    v += dpp_f<0x4E>(v);
    v += dpp_f<0x141>(v);
    v += dpp_f<0x140>(v);
    v += dpp_f<0x142>(v);
    v += dpp_f<0x143>(v);
    return v;  // lane 63 correct
}

// One Sinkhorn "phase": softmin_eps(C,h) for all rows of both sides, damped.
// Fused single pass with estimator stabilizer m_est (prev phase's LSE scaled
// by eps ratio). Band-validated: s in (1e-30,1e34) => full fp32 precision;
// else exact 2-pass redo (deterministically exercised by the init phase).
__global__ __launch_bounds__(THREADS, 8) void sinkhorn_phase(
    const float* __restrict__ x, const float* __restrict__ y,
    const float* __restrict__ loga, const float* __restrict__ logb,
    const float* __restrict__ f_prev, const float* __restrict__ g_prev,
    float* __restrict__ f_next, float* __restrict__ g_next,
    float* __restrict__ Ls,          // [2][NB][NPTS] log2-domain LSE store
    float eps, float inv_eps, float c_old, float c_new,
    float mscale, int initPhase)
{
    __shared__ float4 tile[NPTS];   // {y.x, y.y, hc(log2), pad}

    const int blk = blockIdx.x;
    const int side = blk >> 9;          // 512 blocks/side
    const int rblk = blk & 511;
    const int batch = rblk >> 6;        // 64 row-tiles (32 rows) per batch
    const int rowTile = rblk & 63;

    const float* rowPts; const float* colPts; const float* hlog;
    const float* hpot; const float* ownPrev; float* outPot;
    if (side == 0) { rowPts=x; colPts=y; hlog=logb; hpot=g_prev; ownPrev=f_prev; outPot=f_next; }
    else           { rowPts=y; colPts=x; hlog=loga; hpot=f_prev; ownPrev=g_prev; outPot=g_next; }

    const float LOG2E = 1.4426950408889634f;
    const float LN2 = 0.69314718055994531f;

    // Stage columns + log2-domain column constant into LDS (4 iters).
    const float2* cp2 = (const float2*)(colPts + (size_t)batch*NPTS*2);
    const float* hl = hlog + (size_t)batch*NPTS;
    const float* pp = hpot + (size_t)batch*NPTS;
    for (int j = threadIdx.x; j < NPTS; j += THREADS) {
        float2 p = cp2[j];
        float hp = initPhase ? 0.0f : pp[j] * inv_eps;
        float hcv = (hl[j] + hp - 0.5f*inv_eps*fmaf(p.x, p.x, p.y*p.y)) * LOG2E;
        tile[j] = make_float4(p.x, p.y, hcv, 0.0f);
    }
    __syncthreads();

    const int lane = threadIdx.x & 63;
    const int wv = threadIdx.x >> 6;                 // 8 waves/block
    const int row0 = rowTile*32 + wv*RPW;
    const int gidx0 = batch*NPTS + row0;
    const float2* rp2 = (const float2*)(rowPts + (size_t)batch*NPTS*2) + row0;
    const float* Lp = Ls + side*NE + gidx0;

    const float sc = inv_eps * LOG2E;
    float rx[RPW], ry[RPW], mest[RPW], s[RPW];
    #pragma unroll
    for (int r = 0; r < RPW; r++) {
        float2 p = rp2[r];
        rx[r] = p.x * sc;
        ry[r] = p.y * sc;
        mest[r] = initPhase ? 200.0f : Lp[r] * mscale;
        s[r] = 0.0f;
    }

    // Fused pass: 2 fma + 1 sub + 1 exp2 + 1 add per (row, j) element.
    #pragma unroll 4
    for (int it = 0; it < NPTS/64; it++) {
        float4 t4 = tile[(it << 6) + lane];
        #pragma unroll
        for (int r = 0; r < RPW; r++) {
            float t = fmaf(rx[r], t4.x, fmaf(ry[r], t4.y, t4.z)) - mest[r];
            s[r] += FAST_EXP2(t);
        }
    }
    #pragma unroll
    for (int r = 0; r < RPW; r++) s[r] = wred_sum(s[r]);

    int bad = 0;
    if (lane == 63) {
        #pragma unroll
        for (int r = 0; r < RPW; r++)
            bad |= !(s[r] > 1e-30f && s[r] < 1e34f);
    }
    if (__any(bad)) {
        // Exact 2-pass redo (wave-local; tile unchanged, no barrier needed).
        float mm[RPW];
        #pragma unroll
        for (int r = 0; r < RPW; r++) mm[r] = -3.4e38f;
        #pragma unroll 4
        for (int it = 0; it < NPTS/64; it++) {
            float4 t4 = tile[(it << 6) + lane];
            #pragma unroll
            for (int r = 0; r < RPW; r++) {
                float t = fmaf(rx[r], t4.x, fmaf(ry[r], t4.y, t4.z)) - mest[r];
                mm[r] = fmaxf(mm[r], t);
            }
        }
        #pragma unroll
        for (int r = 0; r < RPW; r++) {
            mm[r] = wred_max(mm[r]);
            mm[r] = __shfl(mm[r], 63);   // broadcast shifted max
            s[r] = 0.0f;
        }
        #pragma unroll 4
        for (int it = 0; it < NPTS/64; it++) {
            float4 t4 = tile[(it << 6) + lane];
            #pragma unroll
            for (int r = 0; r < RPW; r++) {
                float t = fmaf(rx[r], t4.x, fmaf(ry[r], t4.y, t4.z)) - mest[r];
                s[r] += FAST_EXP2(t - mm[r]);
            }
        }
        #pragma unroll
        for (int r = 0; r < RPW; r++) {
            s[r] = wred_sum(s[r]);
            mest[r] += mm[r];            // final L = mest + mm + log2(s)
        }
    }

    if (lane == 63) {
        #pragma unroll
        for (int r = 0; r < RPW; r++) {
            float2 p = rp2[r];                            // hr recomputed here
            float hr = -0.5f * sc * fmaf(p.x, p.x, p.y * p.y);
            float L = mest[r] + FAST_LOG2(s[r]);          // log2-domain LSE
            float sm = -eps * LN2 * (hr + L);             // softmin value
            outPot[gidx0 + r] = c_old * ownPrev[gidx0 + r] + c_new * sm;
            Ls[side*NE + gidx0 + r] = L;                  // estimator for next phase
        }
    }
}

__global__ void log_precompute(const float* __restrict__ a, const float* __restrict__ b,
                               float* __restrict__ loga, float* __restrict__ logb, int n)
{
    int i = blockIdx.x * blockDim.x + threadIdx.x;
    if (i < n) {
        loga[i] = logf(a[i]);
        logb[i] = logf(b[i]);
    }
}

__global__ __launch_bounds__(1024) void loss_reduce(
    const float* __restrict__ a, const float* __restrict__ bw,
    const float* __restrict__ f, const float* __restrict__ g,
    float* __restrict__ out)
{
    const float4* a4 = (const float4*)a;
    const float4* b4 = (const float4*)bw;
    const float4* f4 = (const float4*)f;
    const float4* g4 = (const float4*)g;
    float acc = 0.0f;
    for (int i = threadIdx.x; i < NE/4; i += 1024) {
        float4 av = a4[i], fv = f4[i], bv = b4[i], gv = g4[i];
        acc += av.x*fv.x + av.y*fv.y + av.z*fv.z + av.w*fv.w;
        acc += bv.x*gv.x + bv.y*gv.y + bv.z*gv.z + bv.w*gv.w;
    }
    acc += __shfl_xor(acc, 32);
    acc += __shfl_xor(acc, 16);
    acc += __shfl_xor(acc, 8);
    acc += __shfl_xor(acc, 4);
    acc += __shfl_xor(acc, 2);
    acc += __shfl_xor(acc, 1);
    __shared__ float wsum[16];
    int wid = threadIdx.x >> 6;
    if ((threadIdx.x & 63) == 0) wsum[wid] = acc;
    __syncthreads();
    if (threadIdx.x < 16) {
        float v = wsum[threadIdx.x];
        v += __shfl_xor(v, 8, 16);
        v += __shfl_xor(v, 4, 16);
        v += __shfl_xor(v, 2, 16);
        v += __shfl_xor(v, 1, 16);
        if (threadIdx.x == 0) out[0] = v * (1.0f / NB);
    }
}

extern "C" void kernel_launch(void* const* d_in, const int* in_sizes, int n_in,
                              void* d_out, int out_size, void* d_ws, size_t ws_size,
                              hipStream_t stream)
{
    const float* a = (const float*)d_in[0];
    const float* x = (const float*)d_in[1];
    const float* b = (const float*)d_in[2];
    const float* y = (const float*)d_in[3];
    float* out = (float*)d_out;

    float* ws = (float*)d_ws;
    float* loga = ws + 0 * NE;
    float* logb = ws + 1 * NE;
    float* fA   = ws + 2 * NE;
    float* gA   = ws + 3 * NE;
    float* fB   = ws + 4 * NE;
    float* gB   = ws + 5 * NE;
    float* Ls   = ws + 6 * NE;      // 2*NE floats

    // eps annealing schedule (host-side, as in reference)
    double eps_list[32];
    int ne = 0;
    const double eps_final = 0.05 * 0.05;   // blur^p
    double eps = 2.0 * 2.0;                  // diameter^p
    while (eps > eps_final) { eps_list[ne++] = eps; eps *= 0.64; }  // scaling^p
    eps_list[ne++] = eps_final;              // ne == 18

    log_precompute<<<(NE + 255) / 256, 256, 0, stream>>>(a, b, loga, logb, NE);

    const float* fp = fA; const float* gp = gA;
    float* fn = fB; float* gn = gB;

    auto phase = [&](double e, double e_prev, float c_old, float c_new, int init) {
        sinkhorn_phase<<<1024, THREADS, 0, stream>>>(
            x, y, loga, logb, fp, gp, fn, gn, Ls,
            (float)e, (float)(1.0 / e), c_old, c_new,
            (float)(e_prev / e), init);
    };
    auto swapbuf = [&]() {
        const float* tf = fp; const float* tg = gp;
        fp = fn; gp = gn;
        fn = (float*)tf; gn = (float*)tg;
    };

    // init at eps0 (no potentials read; forced redo validates fallback path)
    phase(eps_list[0], eps_list[0], 0.0f, 1.0f, 1);
    swapbuf();
    // annealed damped iterations
    double e_prev = eps_list[0];
    for (int k = 0; k < ne; k++) {
        phase(eps_list[k], e_prev, 0.5f, 0.5f, 0);
        e_prev = eps_list[k];
        swapbuf();
    }
    // final extrapolation at eps_final (no damping)
    phase(eps_list[ne - 1], e_prev, 0.0f, 1.0f, 0);
    // result potentials are in fn, gn

    loss_reduce<<<1, 1024, 0, stream>>>(a, b, fn, gn, out);
}